// Round 1
// baseline (1073.635 us; speedup 1.0000x reference)
//
#include <hip/hip_runtime.h>
#include <math.h>

#define N_NODES 50000
#define N_EDGES 800000
#define D 64

// ---- order-preserving float<->uint for atomicMax on signed floats ----
__device__ __forceinline__ unsigned fkey(float f) {
    unsigned b = __float_as_uint(f);
    return (b & 0x80000000u) ? ~b : (b | 0x80000000u);
}
__device__ __forceinline__ float funkey(unsigned u) {
    unsigned b = (u & 0x80000000u) ? (u ^ 0x80000000u) : ~u;
    return __uint_as_float(b);
}

// K1: z = h @ W.T + b  (row-local, safe in-place when h==z),
//     s_src[n] = z[n]·a[0:64], s_dst[n] = z[n]·a[64:128] + ab
template<int ROWS_PER_WAVE>
__global__ void node_linear(const float* h, float* z,
                            const float* __restrict__ W, const float* __restrict__ b,
                            const float* __restrict__ a, const float* __restrict__ ab,
                            float* __restrict__ s_src, float* __restrict__ s_dst) {
    __shared__ float Wl[D * 65];   // pad stride 65 -> 2-way LDS conflict (free)
    for (int i = threadIdx.x; i < D * D; i += blockDim.x) {
        int r = i >> 6, c = i & 63;
        Wl[r * 65 + c] = W[i];
    }
    __syncthreads();
    const int lane = threadIdx.x & 63;
    const int wid  = blockIdx.x * (blockDim.x >> 6) + (threadIdx.x >> 6);
    const float bj  = b[lane];
    const float alo = a[lane];
    const float ahi = a[64 + lane];
    const float abv = ab[0];
    const int row0 = wid * ROWS_PER_WAVE;
    for (int r = 0; r < ROWS_PER_WAVE; ++r) {
        const int row = row0 + r;
        if (row >= N_NODES) return;
        const float hreg = h[row * D + lane];
        float acc = bj;
        #pragma unroll
        for (int k = 0; k < D; ++k) {
            const float hv = __shfl(hreg, k, 64);
            acc = fmaf(hv, Wl[lane * 65 + k], acc);
        }
        // wave-reduce attention scalars
        float t0 = acc * alo, t1 = acc * ahi;
        #pragma unroll
        for (int off = 32; off >= 1; off >>= 1) {
            t0 += __shfl_xor(t0, off, 64);
            t1 += __shfl_xor(t1, off, 64);
        }
        z[row * D + lane] = acc;
        if (lane == 0) { s_src[row] = t0; s_dst[row] = t1 + abv; }
    }
}

// K2: per-edge logit + segment-max via uint atomicMax
__global__ void edge_logits(const int* __restrict__ src, const int* __restrict__ dst,
                            const float* __restrict__ s_src, const float* __restrict__ s_dst,
                            float* __restrict__ e_buf, unsigned* __restrict__ m_u) {
    const int i = blockIdx.x * blockDim.x + threadIdx.x;
    if (i >= N_EDGES) return;
    const int s = src[i], d = dst[i];
    float e = s_src[s] + s_dst[d];
    e = e > 0.f ? e : 0.01f * e;         // leaky_relu(0.01)
    e_buf[i] = e;
    atomicMax(&m_u[d], fkey(e));
}

// K3: ex = exp(e - m[dst]); den[dst] += ex; acc[dst,:] += ex * z[src,:]
template<int EDGES_PER_WAVE>
__global__ void edge_aggregate(const int* __restrict__ src, const int* __restrict__ dst,
                               const float* __restrict__ e_buf, const unsigned* __restrict__ m_u,
                               const float* __restrict__ z, float* __restrict__ den,
                               float* __restrict__ acc) {
    const int lane = threadIdx.x & 63;
    const int wid  = blockIdx.x * (blockDim.x >> 6) + (threadIdx.x >> 6);
    const int base = wid * EDGES_PER_WAVE;
    for (int t = 0; t < EDGES_PER_WAVE; ++t) {
        const int i = base + t;
        if (i >= N_EDGES) return;
        const int s = src[i], d = dst[i];
        const float m  = funkey(m_u[d]);
        const float ex = expf(e_buf[i] - m);
        if (lane == 0) atomicAdd(&den[d], ex);
        atomicAdd(&acc[d * D + lane], ex * z[s * D + lane]);
    }
}

// K4: out = acc/den (+optional relu); den==0 (isolated node) -> 0
template<bool RELU>
__global__ void node_norm(const float* __restrict__ acc, const float* __restrict__ den,
                          float* __restrict__ out) {
    const int idx = blockIdx.x * blockDim.x + threadIdx.x;
    if (idx >= N_NODES * D) return;
    const float dn = den[idx >> 6];
    float v = (dn > 0.f) ? acc[idx] / dn : 0.f;
    if (RELU) v = fmaxf(v, 0.f);
    out[idx] = v;
}

extern "C" void kernel_launch(void* const* d_in, const int* in_sizes, int n_in,
                              void* d_out, int out_size, void* d_ws, size_t ws_size,
                              hipStream_t stream) {
    const float* x   = (const float*)d_in[0];
    const int*   src = (const int*)d_in[1];
    const int*   dst = (const int*)d_in[2];
    float* out = (float*)d_out;

    // workspace carve-out (~17 MB)
    char* w = (char*)d_ws;
    float* zbuf = (float*)w;  w += (size_t)N_NODES * D * sizeof(float);
    float* e_buf = (float*)w; w += (size_t)N_EDGES * sizeof(float);
    float* s_src = (float*)w; w += (size_t)N_NODES * sizeof(float);
    float* s_dst = (float*)w; w += (size_t)N_NODES * sizeof(float);
    float* den   = (float*)w; w += (size_t)N_NODES * sizeof(float);
    unsigned* m_u = (unsigned*)w; w += (size_t)N_NODES * sizeof(unsigned);

    const int ROWS_PER_WAVE = 16;
    const int grid_k1 = (N_NODES + 4 * ROWS_PER_WAVE - 1) / (4 * ROWS_PER_WAVE); // 782
    const int grid_k2 = (N_EDGES + 255) / 256;                                    // 3125
    const int EDGES_PER_WAVE = 4;
    const int grid_k3 = (N_EDGES + 4 * EDGES_PER_WAVE - 1) / (4 * EDGES_PER_WAVE); // 50000
    const int grid_k4 = (N_NODES * D + 255) / 256;                                 // 12500

    for (int layer = 0; layer < 3; ++layer) {
        const float* W  = (const float*)d_in[3 + 4 * layer];
        const float* b  = (const float*)d_in[4 + 4 * layer];
        const float* a  = (const float*)d_in[5 + 4 * layer];
        const float* ab = (const float*)d_in[6 + 4 * layer];
        const float* hin = (layer == 0) ? x : zbuf;

        hipMemsetAsync(m_u, 0, (size_t)N_NODES * 4, stream);   // 0 == fkey(-inf) lower bound
        hipMemsetAsync(den, 0, (size_t)N_NODES * 4, stream);
        hipMemsetAsync(out, 0, (size_t)N_NODES * D * 4, stream); // acc buffer = d_out

        node_linear<ROWS_PER_WAVE><<<grid_k1, 256, 0, stream>>>(hin, zbuf, W, b, a, ab, s_src, s_dst);
        edge_logits<<<grid_k2, 256, 0, stream>>>(src, dst, s_src, s_dst, e_buf, m_u);
        edge_aggregate<EDGES_PER_WAVE><<<grid_k3, 256, 0, stream>>>(src, dst, e_buf, m_u, zbuf, den, out);
        if (layer < 2) {
            node_norm<true><<<grid_k4, 256, 0, stream>>>(out, den, zbuf);  // h for next layer
        } else {
            node_norm<false><<<grid_k4, 256, 0, stream>>>(out, den, out);  // final, in place
        }
    }
}

// Round 2
// 597.780 us; speedup vs baseline: 1.7960x; 1.7960x over previous
//
#include <hip/hip_runtime.h>
#include <math.h>

#define N_NODES 50000
#define N_EDGES 800000
#define D 64

// ============================================================
// CSR build (once per call; dst is shared by all 3 layers)
// ============================================================
__global__ void hist_kernel(const int* __restrict__ dst, int* __restrict__ counts) {
    const int i = blockIdx.x * blockDim.x + threadIdx.x;
    if (i < N_EDGES) atomicAdd(&counts[dst[i]], 1);
}

// single block of 1024 threads: exclusive scan of 50000 counts
__global__ void scan_kernel(const int* __restrict__ counts, int* __restrict__ row_ptr,
                            int* __restrict__ cursor) {
    __shared__ int part[1024];
    const int tid = threadIdx.x;
    const int CHUNK = (N_NODES + 1023) / 1024;   // 49
    const int beg = tid * CHUNK;
    const int end = min(beg + CHUNK, N_NODES);
    int s = 0;
    for (int i = beg; i < end; ++i) s += counts[i];
    part[tid] = s;
    __syncthreads();
    for (int off = 1; off < 1024; off <<= 1) {
        const int w = (tid >= off) ? part[tid - off] : 0;
        __syncthreads();
        part[tid] += w;
        __syncthreads();
    }
    int run = part[tid] - s;                     // exclusive prefix of this chunk
    for (int i = beg; i < end; ++i) {
        row_ptr[i] = run;
        cursor[i]  = run;
        run += counts[i];
    }
    if (tid == 1023) row_ptr[N_NODES] = part[1023];
}

__global__ void scatter_kernel(const int* __restrict__ src, const int* __restrict__ dst,
                               int* __restrict__ cursor, int* __restrict__ csr_src) {
    const int i = blockIdx.x * blockDim.x + threadIdx.x;
    if (i >= N_EDGES) return;
    const int pos = atomicAdd(&cursor[dst[i]], 1);
    csr_src[pos] = src[i];
}

// ============================================================
// K1: z = h @ W.T + b, plus per-node attention scalars
//     s_src[n] = z[n]·a[0:64], s_dst[n] = z[n]·a[64:128] + ab
// ============================================================
template<int ROWS_PER_WAVE>
__global__ void node_linear(const float* __restrict__ h, float* __restrict__ z,
                            const float* __restrict__ W, const float* __restrict__ b,
                            const float* __restrict__ a, const float* __restrict__ ab,
                            float* __restrict__ s_src, float* __restrict__ s_dst) {
    __shared__ float Wl[D * 65];   // pad stride 65 -> 2-way LDS conflict (free)
    for (int i = threadIdx.x; i < D * D; i += blockDim.x) {
        const int r = i >> 6, c = i & 63;
        Wl[r * 65 + c] = W[i];
    }
    __syncthreads();
    const int lane = threadIdx.x & 63;
    const int wid  = blockIdx.x * (blockDim.x >> 6) + (threadIdx.x >> 6);
    const float bj  = b[lane];
    const float alo = a[lane];
    const float ahi = a[64 + lane];
    const float abv = ab[0];
    const int row0 = wid * ROWS_PER_WAVE;
    for (int r = 0; r < ROWS_PER_WAVE; ++r) {
        const int row = row0 + r;
        if (row >= N_NODES) return;
        const float hreg = h[row * D + lane];
        float acc = bj;
        #pragma unroll
        for (int k = 0; k < D; ++k) {
            const float hv = __shfl(hreg, k, 64);
            acc = fmaf(hv, Wl[lane * 65 + k], acc);
        }
        float t0 = acc * alo, t1 = acc * ahi;
        #pragma unroll
        for (int off = 32; off >= 1; off >>= 1) {
            t0 += __shfl_xor(t0, off, 64);
            t1 += __shfl_xor(t1, off, 64);
        }
        z[row * D + lane] = acc;
        if (lane == 0) { s_src[row] = t0; s_dst[row] = t1 + abv; }
    }
}

// ============================================================
// K2: fused per-dst-node softmax + aggregate + normalize (+ReLU)
//     one wave per destination node; zero atomics
// ============================================================
template<bool RELU>
__global__ void gat_aggregate(const int* __restrict__ row_ptr, const int* __restrict__ csr_src,
                              const float* __restrict__ s_src, const float* __restrict__ s_dst,
                              const float* __restrict__ z, float* __restrict__ out) {
    const int lane = threadIdx.x & 63;
    const int node = blockIdx.x * (blockDim.x >> 6) + (threadIdx.x >> 6);
    if (node >= N_NODES) return;
    const int beg = row_ptr[node];
    const int end = row_ptr[node + 1];
    if (beg == end) { out[node * D + lane] = 0.f; return; }   // isolated node -> 0
    const float sd = s_dst[node];
    float m = -INFINITY;
    float den = 0.f;    // per-lane partial, reduced at the end
    float acc = 0.f;    // feature accumulator (lane = feature)
    for (int base = beg; base < end; base += 64) {
        const int n = min(64, end - base);
        const int sidx = (lane < n) ? csr_src[base + lane] : 0;
        float e = -INFINITY;
        if (lane < n) {
            e = s_src[sidx] + sd;
            e = e > 0.f ? e : 0.01f * e;     // leaky_relu
        }
        // wave max of this chunk
        float mc = e;
        #pragma unroll
        for (int off = 32; off >= 1; off >>= 1) mc = fmaxf(mc, __shfl_xor(mc, off, 64));
        if (mc > m) {                        // online-softmax rescale (first chunk: exp(-inf)=0)
            const float scale = __expf(m - mc);
            den *= scale; acc *= scale; m = mc;
        }
        const float ex = __expf(e - m);      // 0 for invalid lanes (e = -inf)
        den += ex;
        for (int t = 0; t < n; ++t) {
            const float ext = __shfl(ex, t, 64);
            const int   st  = __shfl(sidx, t, 64);
            acc = fmaf(ext, z[st * D + lane], acc);
        }
    }
    #pragma unroll
    for (int off = 32; off >= 1; off >>= 1) den += __shfl_xor(den, off, 64);
    float v = acc / den;
    if (RELU) v = fmaxf(v, 0.f);
    out[node * D + lane] = v;
}

// ============================================================
extern "C" void kernel_launch(void* const* d_in, const int* in_sizes, int n_in,
                              void* d_out, int out_size, void* d_ws, size_t ws_size,
                              hipStream_t stream) {
    const float* x   = (const float*)d_in[0];
    const int*   src = (const int*)d_in[1];
    const int*   dst = (const int*)d_in[2];
    float* out = (float*)d_out;

    // workspace carve-out (~17 MB)
    char* w = (char*)d_ws;
    float* zbuf    = (float*)w; w += (size_t)N_NODES * D * sizeof(float);
    float* s_src   = (float*)w; w += (size_t)N_NODES * sizeof(float);
    float* s_dst   = (float*)w; w += (size_t)N_NODES * sizeof(float);
    int*   counts  = (int*)w;   w += (size_t)N_NODES * sizeof(int);
    int*   row_ptr = (int*)w;   w += (size_t)(N_NODES + 1) * sizeof(int);
    int*   cursor  = (int*)w;   w += (size_t)N_NODES * sizeof(int);
    int*   csr_src = (int*)w;   w += (size_t)N_EDGES * sizeof(int);

    // ---- CSR build (dst shared by all layers) ----
    hipMemsetAsync(counts, 0, (size_t)N_NODES * sizeof(int), stream);
    hist_kernel<<<(N_EDGES + 255) / 256, 256, 0, stream>>>(dst, counts);
    scan_kernel<<<1, 1024, 0, stream>>>(counts, row_ptr, cursor);
    scatter_kernel<<<(N_EDGES + 255) / 256, 256, 0, stream>>>(src, dst, cursor, csr_src);

    const int ROWS_PER_WAVE = 16;
    const int grid_k1  = (N_NODES + 4 * ROWS_PER_WAVE - 1) / (4 * ROWS_PER_WAVE); // 782
    const int grid_agg = (N_NODES + 3) / 4;                                        // 12500

    for (int layer = 0; layer < 3; ++layer) {
        const float* W  = (const float*)d_in[3 + 4 * layer];
        const float* b  = (const float*)d_in[4 + 4 * layer];
        const float* a  = (const float*)d_in[5 + 4 * layer];
        const float* ab = (const float*)d_in[6 + 4 * layer];
        const float* hin = (layer == 0) ? x : out;   // d_out doubles as h buffer

        node_linear<ROWS_PER_WAVE><<<grid_k1, 256, 0, stream>>>(hin, zbuf, W, b, a, ab, s_src, s_dst);
        if (layer < 2) {
            gat_aggregate<true ><<<grid_agg, 256, 0, stream>>>(row_ptr, csr_src, s_src, s_dst, zbuf, out);
        } else {
            gat_aggregate<false><<<grid_agg, 256, 0, stream>>>(row_ptr, csr_src, s_src, s_dst, zbuf, out);
        }
    }
}

// Round 3
// 502.174 us; speedup vs baseline: 2.1380x; 1.1904x over previous
//
#include <hip/hip_runtime.h>
#include <math.h>

#define N_NODES 50000
#define N_EDGES 800000
#define D 64

#define SCAN_BLOCK 256
#define SCAN_TILE  1024                       // 4 items/thread
#define N_TILES    ((N_NODES + SCAN_TILE - 1) / SCAN_TILE)   // 49

// ============================================================
// CSR build (once per call; dst is shared by all 3 layers)
// ============================================================
__global__ void hist_kernel(const int* __restrict__ dst, int* __restrict__ counts) {
    const int i = blockIdx.x * blockDim.x + threadIdx.x;
    if (i < N_EDGES) atomicAdd(&counts[dst[i]], 1);
}

// pass 1: per-tile sums (coalesced int4 loads + wave/block reduce)
__global__ void scan_partial(const int* __restrict__ counts, int* __restrict__ partials) {
    const int tile = blockIdx.x;
    const int base = tile * SCAN_TILE + threadIdx.x * 4;
    int4 c = make_int4(0, 0, 0, 0);
    if (base + 3 < N_NODES) c = *(const int4*)&counts[base];
    else {
        int* cp = (int*)&c;
        for (int j = 0; j < 4; ++j) if (base + j < N_NODES) cp[j] = counts[base + j];
    }
    int s = c.x + c.y + c.z + c.w;
    #pragma unroll
    for (int off = 32; off >= 1; off >>= 1) s += __shfl_xor(s, off, 64);
    __shared__ int red[SCAN_BLOCK / 64];
    if ((threadIdx.x & 63) == 0) red[threadIdx.x >> 6] = s;
    __syncthreads();
    if (threadIdx.x == 0) {
        int t = 0;
        #pragma unroll
        for (int i = 0; i < SCAN_BLOCK / 64; ++i) t += red[i];
        partials[tile] = t;
    }
}

// pass 2: one wave scans the tile sums (exclusive, in place) + writes row_ptr[N]
__global__ void scan_offsets(int* __restrict__ partials, int* __restrict__ row_ptr_last) {
    const int lane = threadIdx.x;
    const int v = (lane < N_TILES) ? partials[lane] : 0;
    int inc = v;
    #pragma unroll
    for (int off = 1; off < 64; off <<= 1) {
        const int w = __shfl_up(inc, off, 64);
        if (lane >= off) inc += w;
    }
    if (lane < N_TILES) partials[lane] = inc - v;   // exclusive tile offset
    if (lane == 63) *row_ptr_last = inc;            // total (= N_EDGES)
}

// pass 3: block-local exclusive scan + tile offset -> row_ptr, cursor
__global__ void scan_write(const int* __restrict__ counts, const int* __restrict__ partials,
                           int* __restrict__ row_ptr, int* __restrict__ cursor) {
    const int tile = blockIdx.x;
    const int tid  = threadIdx.x;
    const int base = tile * SCAN_TILE + tid * 4;
    int4 c = make_int4(0, 0, 0, 0);
    if (base + 3 < N_NODES) c = *(const int4*)&counts[base];
    else {
        int* cp = (int*)&c;
        for (int j = 0; j < 4; ++j) if (base + j < N_NODES) cp[j] = counts[base + j];
    }
    const int s = c.x + c.y + c.z + c.w;
    __shared__ int sh[SCAN_BLOCK];
    sh[tid] = s;
    __syncthreads();
    for (int off = 1; off < SCAN_BLOCK; off <<= 1) {
        const int w = (tid >= off) ? sh[tid - off] : 0;
        __syncthreads();
        sh[tid] += w;
        __syncthreads();
    }
    int run = partials[tile] + sh[tid] - s;   // global exclusive prefix
    const int* cp = (const int*)&c;
    int rp[4];
    #pragma unroll
    for (int j = 0; j < 4; ++j) { rp[j] = run; run += cp[j]; }
    if (base + 3 < N_NODES) {
        *(int4*)&row_ptr[base] = make_int4(rp[0], rp[1], rp[2], rp[3]);
        *(int4*)&cursor[base]  = make_int4(rp[0], rp[1], rp[2], rp[3]);
    } else {
        for (int j = 0; j < 4; ++j)
            if (base + j < N_NODES) { row_ptr[base + j] = rp[j]; cursor[base + j] = rp[j]; }
    }
}

__global__ void scatter_kernel(const int* __restrict__ src, const int* __restrict__ dst,
                               int* __restrict__ cursor, int* __restrict__ csr_src) {
    const int i = blockIdx.x * blockDim.x + threadIdx.x;
    if (i >= N_EDGES) return;
    const int pos = atomicAdd(&cursor[dst[i]], 1);
    csr_src[pos] = src[i];
}

// ============================================================
// K1: z = h @ W.T + b, plus per-node attention scalars
// ============================================================
template<int ROWS_PER_WAVE>
__global__ void node_linear(const float* __restrict__ h, float* __restrict__ z,
                            const float* __restrict__ W, const float* __restrict__ b,
                            const float* __restrict__ a, const float* __restrict__ ab,
                            float* __restrict__ s_src, float* __restrict__ s_dst) {
    __shared__ float Wl[D * 65];
    for (int i = threadIdx.x; i < D * D; i += blockDim.x) {
        const int r = i >> 6, c = i & 63;
        Wl[r * 65 + c] = W[i];
    }
    __syncthreads();
    const int lane = threadIdx.x & 63;
    const int wid  = blockIdx.x * (blockDim.x >> 6) + (threadIdx.x >> 6);
    const float bj  = b[lane];
    const float alo = a[lane];
    const float ahi = a[64 + lane];
    const float abv = ab[0];
    const int row0 = wid * ROWS_PER_WAVE;
    for (int r = 0; r < ROWS_PER_WAVE; ++r) {
        const int row = row0 + r;
        if (row >= N_NODES) return;
        const float hreg = h[row * D + lane];
        float acc = bj;
        #pragma unroll
        for (int k = 0; k < D; ++k) {
            const float hv = __shfl(hreg, k, 64);
            acc = fmaf(hv, Wl[lane * 65 + k], acc);
        }
        float t0 = acc * alo, t1 = acc * ahi;
        #pragma unroll
        for (int off = 32; off >= 1; off >>= 1) {
            t0 += __shfl_xor(t0, off, 64);
            t1 += __shfl_xor(t1, off, 64);
        }
        z[row * D + lane] = acc;
        if (lane == 0) { s_src[row] = t0; s_dst[row] = t1 + abv; }
    }
}

// ============================================================
// K2: fused per-dst-node softmax + aggregate + normalize (+ReLU)
// ============================================================
template<bool RELU>
__global__ void gat_aggregate(const int* __restrict__ row_ptr, const int* __restrict__ csr_src,
                              const float* __restrict__ s_src, const float* __restrict__ s_dst,
                              const float* __restrict__ z, float* __restrict__ out) {
    const int lane = threadIdx.x & 63;
    const int node = blockIdx.x * (blockDim.x >> 6) + (threadIdx.x >> 6);
    if (node >= N_NODES) return;
    const int beg = row_ptr[node];
    const int end = row_ptr[node + 1];
    if (beg == end) { out[node * D + lane] = 0.f; return; }
    const float sd = s_dst[node];
    float m = -INFINITY;
    float den = 0.f;
    float acc = 0.f;
    for (int base = beg; base < end; base += 64) {
        const int n = min(64, end - base);
        const int sidx = (lane < n) ? csr_src[base + lane] : 0;
        float e = -INFINITY;
        if (lane < n) {
            e = s_src[sidx] + sd;
            e = e > 0.f ? e : 0.01f * e;
        }
        float mc = e;
        #pragma unroll
        for (int off = 32; off >= 1; off >>= 1) mc = fmaxf(mc, __shfl_xor(mc, off, 64));
        if (mc > m) {
            const float scale = __expf(m - mc);
            den *= scale; acc *= scale; m = mc;
        }
        const float ex = __expf(e - m);
        den += ex;
        for (int t = 0; t < n; ++t) {
            const float ext = __shfl(ex, t, 64);
            const int   st  = __shfl(sidx, t, 64);
            acc = fmaf(ext, z[st * D + lane], acc);
        }
    }
    #pragma unroll
    for (int off = 32; off >= 1; off >>= 1) den += __shfl_xor(den, off, 64);
    float v = acc / den;
    if (RELU) v = fmaxf(v, 0.f);
    out[node * D + lane] = v;
}

// ============================================================
extern "C" void kernel_launch(void* const* d_in, const int* in_sizes, int n_in,
                              void* d_out, int out_size, void* d_ws, size_t ws_size,
                              hipStream_t stream) {
    const float* x   = (const float*)d_in[0];
    const int*   src = (const int*)d_in[1];
    const int*   dst = (const int*)d_in[2];
    float* out = (float*)d_out;

    // workspace carve-out (~17 MB)
    char* w = (char*)d_ws;
    float* zbuf     = (float*)w; w += (size_t)N_NODES * D * sizeof(float);
    float* s_src    = (float*)w; w += (size_t)N_NODES * sizeof(float);
    float* s_dst    = (float*)w; w += (size_t)N_NODES * sizeof(float);
    int*   counts   = (int*)w;   w += (size_t)N_NODES * sizeof(int);
    int*   row_ptr  = (int*)w;   w += (size_t)(N_NODES + 1) * sizeof(int);
    int*   cursor   = (int*)w;   w += (size_t)N_NODES * sizeof(int);
    int*   csr_src  = (int*)w;   w += (size_t)N_EDGES * sizeof(int);
    int*   partials = (int*)w;   w += (size_t)N_TILES * sizeof(int);

    // ---- CSR build (dst shared by all layers) ----
    hipMemsetAsync(counts, 0, (size_t)N_NODES * sizeof(int), stream);
    hist_kernel<<<(N_EDGES + 255) / 256, 256, 0, stream>>>(dst, counts);
    scan_partial<<<N_TILES, SCAN_BLOCK, 0, stream>>>(counts, partials);
    scan_offsets<<<1, 64, 0, stream>>>(partials, &row_ptr[N_NODES]);
    scan_write<<<N_TILES, SCAN_BLOCK, 0, stream>>>(counts, partials, row_ptr, cursor);
    scatter_kernel<<<(N_EDGES + 255) / 256, 256, 0, stream>>>(src, dst, cursor, csr_src);

    const int ROWS_PER_WAVE = 16;
    const int grid_k1  = (N_NODES + 4 * ROWS_PER_WAVE - 1) / (4 * ROWS_PER_WAVE); // 782
    const int grid_agg = (N_NODES + 3) / 4;                                        // 12500

    for (int layer = 0; layer < 3; ++layer) {
        const float* W  = (const float*)d_in[3 + 4 * layer];
        const float* b  = (const float*)d_in[4 + 4 * layer];
        const float* a  = (const float*)d_in[5 + 4 * layer];
        const float* ab = (const float*)d_in[6 + 4 * layer];
        const float* hin = (layer == 0) ? x : out;   // d_out doubles as h buffer

        node_linear<ROWS_PER_WAVE><<<grid_k1, 256, 0, stream>>>(hin, zbuf, W, b, a, ab, s_src, s_dst);
        if (layer < 2) {
            gat_aggregate<true ><<<grid_agg, 256, 0, stream>>>(row_ptr, csr_src, s_src, s_dst, zbuf, out);
        } else {
            gat_aggregate<false><<<grid_agg, 256, 0, stream>>>(row_ptr, csr_src, s_src, s_dst, zbuf, out);
        }
    }
}

// Round 4
// 402.655 us; speedup vs baseline: 2.6664x; 1.2472x over previous
//
#include <hip/hip_runtime.h>
#include <math.h>

#define N_NODES 50000
#define N_EDGES 800000
#define D 64

#define SCAN_BLOCK 256
#define SCAN_TILE  1024
#define N_TILES    ((N_NODES + SCAN_TILE - 1) / SCAN_TILE)   // 49

// ============================================================
// CSR build (once per call; dst is shared by all 3 layers)
// ============================================================
__global__ void hist_kernel(const int* __restrict__ dst, int* __restrict__ counts) {
    const int i = blockIdx.x * blockDim.x + threadIdx.x;
    if (i < N_EDGES) atomicAdd(&counts[dst[i]], 1);
}

__global__ void scan_partial(const int* __restrict__ counts, int* __restrict__ partials) {
    const int tile = blockIdx.x;
    const int base = tile * SCAN_TILE + threadIdx.x * 4;
    int4 c = make_int4(0, 0, 0, 0);
    if (base + 3 < N_NODES) c = *(const int4*)&counts[base];
    else {
        int* cp = (int*)&c;
        for (int j = 0; j < 4; ++j) if (base + j < N_NODES) cp[j] = counts[base + j];
    }
    int s = c.x + c.y + c.z + c.w;
    #pragma unroll
    for (int off = 32; off >= 1; off >>= 1) s += __shfl_xor(s, off, 64);
    __shared__ int red[SCAN_BLOCK / 64];
    if ((threadIdx.x & 63) == 0) red[threadIdx.x >> 6] = s;
    __syncthreads();
    if (threadIdx.x == 0) {
        int t = 0;
        #pragma unroll
        for (int i = 0; i < SCAN_BLOCK / 64; ++i) t += red[i];
        partials[tile] = t;
    }
}

__global__ void scan_offsets(int* __restrict__ partials, int* __restrict__ row_ptr_last) {
    const int lane = threadIdx.x;
    const int v = (lane < N_TILES) ? partials[lane] : 0;
    int inc = v;
    #pragma unroll
    for (int off = 1; off < 64; off <<= 1) {
        const int w = __shfl_up(inc, off, 64);
        if (lane >= off) inc += w;
    }
    if (lane < N_TILES) partials[lane] = inc - v;
    if (lane == 63) *row_ptr_last = inc;
}

__global__ void scan_write(const int* __restrict__ counts, const int* __restrict__ partials,
                           int* __restrict__ row_ptr, int* __restrict__ cursor) {
    const int tile = blockIdx.x;
    const int tid  = threadIdx.x;
    const int base = tile * SCAN_TILE + tid * 4;
    int4 c = make_int4(0, 0, 0, 0);
    if (base + 3 < N_NODES) c = *(const int4*)&counts[base];
    else {
        int* cp = (int*)&c;
        for (int j = 0; j < 4; ++j) if (base + j < N_NODES) cp[j] = counts[base + j];
    }
    const int s = c.x + c.y + c.z + c.w;
    __shared__ int sh[SCAN_BLOCK];
    sh[tid] = s;
    __syncthreads();
    for (int off = 1; off < SCAN_BLOCK; off <<= 1) {
        const int w = (tid >= off) ? sh[tid - off] : 0;
        __syncthreads();
        sh[tid] += w;
        __syncthreads();
    }
    int run = partials[tile] + sh[tid] - s;
    const int* cp = (const int*)&c;
    int rp[4];
    #pragma unroll
    for (int j = 0; j < 4; ++j) { rp[j] = run; run += cp[j]; }
    if (base + 3 < N_NODES) {
        *(int4*)&row_ptr[base] = make_int4(rp[0], rp[1], rp[2], rp[3]);
        *(int4*)&cursor[base]  = make_int4(rp[0], rp[1], rp[2], rp[3]);
    } else {
        for (int j = 0; j < 4; ++j)
            if (base + j < N_NODES) { row_ptr[base + j] = rp[j]; cursor[base + j] = rp[j]; }
    }
}

__global__ void scatter_kernel(const int* __restrict__ src, const int* __restrict__ dst,
                               int* __restrict__ cursor, int* __restrict__ csr_src) {
    const int i = blockIdx.x * blockDim.x + threadIdx.x;
    if (i >= N_EDGES) return;
    const int pos = atomicAdd(&cursor[dst[i]], 1);
    csr_src[pos] = src[i];
}

// ============================================================
// K1: z = h @ W.T + b  — lane = row, h row in registers,
//     W read at wave-uniform addresses (scalar loads), no LDS/shfl.
//     s_src[n] = z[n]·a[0:64], s_dst[n] = z[n]·a[64:128] + ab
// ============================================================
__global__ __launch_bounds__(64) void node_linear_reg(
    const float* __restrict__ h, float* __restrict__ z,
    const float* __restrict__ W, const float* __restrict__ b,
    const float* __restrict__ a, const float* __restrict__ ab,
    float* __restrict__ s_src, float* __restrict__ s_dst)
{
    const int lane = threadIdx.x;
    const int row  = blockIdx.x * 64 + lane;
    const bool ok  = row < N_NODES;
    const int rsafe = ok ? row : (N_NODES - 1);

    // whole h row in registers: 16 x float4
    float4 hv[16];
    const float4* hp = (const float4*)(h + (size_t)rsafe * D);
    #pragma unroll
    for (int i = 0; i < 16; ++i) hv[i] = hp[i];

    float t0 = 0.f, t1 = 0.f;
    float4* zp = (float4*)(z + (size_t)rsafe * D);

    for (int j4 = 0; j4 < D / 4; ++j4) {          // wave-uniform
        const int j = j4 * 4;
        float acc0 = b[j + 0], acc1 = b[j + 1], acc2 = b[j + 2], acc3 = b[j + 3];
        const float* w0 = &W[(j + 0) * D];
        const float* w1 = &W[(j + 1) * D];
        const float* w2 = &W[(j + 2) * D];
        const float* w3 = &W[(j + 3) * D];
        #pragma unroll
        for (int k4 = 0; k4 < 16; ++k4) {
            const float4 hq = hv[k4];
            const int k = k4 * 4;
            acc0 = fmaf(hq.x, w0[k + 0], acc0); acc0 = fmaf(hq.y, w0[k + 1], acc0);
            acc0 = fmaf(hq.z, w0[k + 2], acc0); acc0 = fmaf(hq.w, w0[k + 3], acc0);
            acc1 = fmaf(hq.x, w1[k + 0], acc1); acc1 = fmaf(hq.y, w1[k + 1], acc1);
            acc1 = fmaf(hq.z, w1[k + 2], acc1); acc1 = fmaf(hq.w, w1[k + 3], acc1);
            acc2 = fmaf(hq.x, w2[k + 0], acc2); acc2 = fmaf(hq.y, w2[k + 1], acc2);
            acc2 = fmaf(hq.z, w2[k + 2], acc2); acc2 = fmaf(hq.w, w2[k + 3], acc2);
            acc3 = fmaf(hq.x, w3[k + 0], acc3); acc3 = fmaf(hq.y, w3[k + 1], acc3);
            acc3 = fmaf(hq.z, w3[k + 2], acc3); acc3 = fmaf(hq.w, w3[k + 3], acc3);
        }
        // attention scalars (a[] is wave-uniform -> scalar loads)
        t0 = fmaf(acc0, a[j + 0], t0); t1 = fmaf(acc0, a[64 + j + 0], t1);
        t0 = fmaf(acc1, a[j + 1], t0); t1 = fmaf(acc1, a[64 + j + 1], t1);
        t0 = fmaf(acc2, a[j + 2], t0); t1 = fmaf(acc2, a[64 + j + 2], t1);
        t0 = fmaf(acc3, a[j + 3], t0); t1 = fmaf(acc3, a[64 + j + 3], t1);
        if (ok) zp[j4] = make_float4(acc0, acc1, acc2, acc3);
    }
    if (ok) { s_src[row] = t0; s_dst[row] = t1 + ab[0]; }
}

// ============================================================
// K2: fused per-dst-node softmax + aggregate + normalize (+ReLU)
// ============================================================
template<bool RELU>
__global__ void gat_aggregate(const int* __restrict__ row_ptr, const int* __restrict__ csr_src,
                              const float* __restrict__ s_src, const float* __restrict__ s_dst,
                              const float* __restrict__ z, float* __restrict__ out) {
    const int lane = threadIdx.x & 63;
    const int node = blockIdx.x * (blockDim.x >> 6) + (threadIdx.x >> 6);
    if (node >= N_NODES) return;
    const int beg = row_ptr[node];
    const int end = row_ptr[node + 1];
    if (beg == end) { out[node * D + lane] = 0.f; return; }
    const float sd = s_dst[node];
    float m = -INFINITY;
    float den = 0.f;
    float acc = 0.f;
    for (int base = beg; base < end; base += 64) {
        const int n = min(64, end - base);
        const int sidx = (lane < n) ? csr_src[base + lane] : 0;
        float e = -INFINITY;
        if (lane < n) {
            e = s_src[sidx] + sd;
            e = e > 0.f ? e : 0.01f * e;
        }
        float mc = e;
        #pragma unroll
        for (int off = 32; off >= 1; off >>= 1) mc = fmaxf(mc, __shfl_xor(mc, off, 64));
        if (mc > m) {
            const float scale = __expf(m - mc);
            den *= scale; acc *= scale; m = mc;
        }
        const float ex = __expf(e - m);
        den += ex;
        for (int t = 0; t < n; ++t) {
            const float ext = __shfl(ex, t, 64);
            const int   st  = __shfl(sidx, t, 64);
            acc = fmaf(ext, z[st * D + lane], acc);
        }
    }
    #pragma unroll
    for (int off = 32; off >= 1; off >>= 1) den += __shfl_xor(den, off, 64);
    float v = acc / den;
    if (RELU) v = fmaxf(v, 0.f);
    out[node * D + lane] = v;
}

// ============================================================
extern "C" void kernel_launch(void* const* d_in, const int* in_sizes, int n_in,
                              void* d_out, int out_size, void* d_ws, size_t ws_size,
                              hipStream_t stream) {
    const float* x   = (const float*)d_in[0];
    const int*   src = (const int*)d_in[1];
    const int*   dst = (const int*)d_in[2];
    float* out = (float*)d_out;

    // workspace carve-out (~17 MB)
    char* w = (char*)d_ws;
    float* zbuf     = (float*)w; w += (size_t)N_NODES * D * sizeof(float);
    float* s_src    = (float*)w; w += (size_t)N_NODES * sizeof(float);
    float* s_dst    = (float*)w; w += (size_t)N_NODES * sizeof(float);
    int*   counts   = (int*)w;   w += (size_t)N_NODES * sizeof(int);
    int*   row_ptr  = (int*)w;   w += (size_t)(N_NODES + 1) * sizeof(int);
    int*   cursor   = (int*)w;   w += (size_t)N_NODES * sizeof(int);
    int*   csr_src  = (int*)w;   w += (size_t)N_EDGES * sizeof(int);
    int*   partials = (int*)w;   w += (size_t)N_TILES * sizeof(int);

    // ---- CSR build (dst shared by all layers) ----
    hipMemsetAsync(counts, 0, (size_t)N_NODES * sizeof(int), stream);
    hist_kernel<<<(N_EDGES + 255) / 256, 256, 0, stream>>>(dst, counts);
    scan_partial<<<N_TILES, SCAN_BLOCK, 0, stream>>>(counts, partials);
    scan_offsets<<<1, 64, 0, stream>>>(partials, &row_ptr[N_NODES]);
    scan_write<<<N_TILES, SCAN_BLOCK, 0, stream>>>(counts, partials, row_ptr, cursor);
    scatter_kernel<<<(N_EDGES + 255) / 256, 256, 0, stream>>>(src, dst, cursor, csr_src);

    const int grid_k1  = (N_NODES + 63) / 64;   // 782 blocks x 1 wave
    const int grid_agg = (N_NODES + 3) / 4;     // 12500

    for (int layer = 0; layer < 3; ++layer) {
        const float* W  = (const float*)d_in[3 + 4 * layer];
        const float* b  = (const float*)d_in[4 + 4 * layer];
        const float* a  = (const float*)d_in[5 + 4 * layer];
        const float* ab = (const float*)d_in[6 + 4 * layer];
        const float* hin = (layer == 0) ? x : out;   // d_out doubles as h buffer

        node_linear_reg<<<grid_k1, 64, 0, stream>>>(hin, zbuf, W, b, a, ab, s_src, s_dst);
        if (layer < 2) {
            gat_aggregate<true ><<<grid_agg, 256, 0, stream>>>(row_ptr, csr_src, s_src, s_dst, zbuf, out);
        } else {
            gat_aggregate<false><<<grid_agg, 256, 0, stream>>>(row_ptr, csr_src, s_src, s_dst, zbuf, out);
        }
    }
}